// Round 9
// baseline (114.859 us; speedup 1.0000x reference)
//
#include <hip/hip_runtime.h>

// AdjacencyAttention: B=4096, N=64, D=256, fp32 in/out.
// Persistent design: grid=256, 1024-thread blocks (16 waves), 1 block/CU
// (guaranteed by 148KB LDS). Each block streams B/256 batches with an
// always-in-flight global_load_lds double-buffered x pipeline.
// KEY: all barriers are raw s_barrier + lgkmcnt-only waits, so the x prefetch
// for batch k+1 stays outstanding across batch k's entire compute (the
// __syncthreads vmcnt(0)-drain was the structural HBM-idle cause).
// Wave w stages AND consumes rows 4w..4w+3 -> buffer handoff = own vmcnt(0).
// Per batch: P1 dots (LDS x) -> barrier -> P3' per-wave in-register
// tanh->bf16 hi/lo t-frags + MFMA (one 16x16 tile per wave; r4-verified
// fragment & store mappings) -> 2-barrier block softmax -> f32x4 stores.

typedef float f32x4 __attribute__((ext_vector_type(4)));
typedef __bf16 bf16x8 __attribute__((ext_vector_type(8)));

typedef __attribute__((address_space(1))) const void gas1_void;
typedef __attribute__((address_space(3))) void las3_void;

#define GLOAD16(gp, lp) \
    __builtin_amdgcn_global_load_lds((gas1_void*)(gp), (las3_void*)(lp), 16, 0, 0)

// raw barrier: LDS-producer ordering only; does NOT drain vmcnt (prefetch lives on)
#define WAIT_LGKM0_BAR()                                         \
    do {                                                         \
        asm volatile("s_waitcnt lgkmcnt(0)" ::: "memory");       \
        __builtin_amdgcn_s_barrier();                            \
        __builtin_amdgcn_sched_barrier(0);                       \
    } while (0)

__global__ __launch_bounds__(1024, 4) void adjatt_kernel(
    const float* __restrict__ x,   // (B,64,256)
    const float* __restrict__ W1,  // (1,)
    const float* __restrict__ W2,  // (256,1)
    const float* __restrict__ W3,  // (256,)
    const float* __restrict__ bs,  // (1,64,64)
    const float* __restrict__ Vs,  // (64,64)
    float* __restrict__ out,       // (B,64,64)
    int B)
{
    __shared__ __align__(16) float xbuf[2][16384];  // 2 x 64KB x double-buffer
    __shared__ __align__(16) float xbs[64 * 65];    // bs, padded stride 65 (bank-spread)
    __shared__ __align__(16) float lr2[64][2];      // {lhs, rhs} per row
    __shared__ float redm[16], reds[16];

    const int tid  = threadIdx.x;
    const int lane = tid & 63;
    const int w    = tid >> 6;     // wave 0..15
    const int l15  = lane & 15;
    const int g    = lane >> 4;    // 0..3
    const int rb   = w & 3;        // s-row block  (Vs rows 16rb..)
    const int cb   = w >> 2;       // s-col block  (t cols 16cb..)
    const int bid  = blockIdx.x;

    // ---------------- prologue ----------------
    // All global loads here are issued BEFORE the x-prefetch, so consuming them
    // emits counted vmcnt waits that leave the prefetch in flight.
    f32x4 w2v[4], w3v[4];
#pragma unroll
    for (int kk = 0; kk < 4; ++kk) {
        w2v[kk] = *(const f32x4*)(W2 + 4 * (l15 + 16 * kk));
        w3v[kk] = *(const f32x4*)(W3 + 4 * (l15 + 16 * kk));
    }
    f32x4 vf0[2], vf1[2];
#pragma unroll
    for (int sk = 0; sk < 2; ++sk) {
        const float* vp = Vs + (16 * rb + l15) * 64 + 32 * sk + 8 * g;
        vf0[sk] = *(const f32x4*)vp;
        vf1[sk] = *(const f32x4*)(vp + 4);
    }
    f32x4 bsv = *(const f32x4*)(bs + 4 * tid);
    const float W1v = W1[0];

    // issue first x prefetch (batch = bid) into xbuf[0]; wave w stages rows 4w..4w+3
    if (bid < B) {
        const float* xs = x + (size_t)bid * 16384;
#pragma unroll
        for (int i = 0; i < 4; ++i)
            GLOAD16(xs + (4 * w + i) * 256 + lane * 4, &xbuf[0][(4 * w + i) * 256]);
    }

    // Vs hi/lo bf16 fragments (B operand; r4-verified layout)
    bf16x8 Vh[2], Vl[2];
#pragma unroll
    for (int sk = 0; sk < 2; ++sk) {
#pragma unroll
        for (int e = 0; e < 4; ++e) {
            __bf16 h0 = (__bf16)vf0[sk][e];
            Vh[sk][e] = h0;
            Vl[sk][e] = (__bf16)(vf0[sk][e] - (float)h0);
            __bf16 h1 = (__bf16)vf1[sk][e];
            Vh[sk][e + 4] = h1;
            Vl[sk][e + 4] = (__bf16)(vf1[sk][e] - (float)h1);
        }
    }

    // stage bs into padded LDS (scalar writes; 4B alignment ok with stride 65)
    {
        const int row = tid >> 4, col = 4 * (tid & 15);
#pragma unroll
        for (int e = 0; e < 4; ++e) xbs[row * 65 + col + e] = bsv[e];
    }
    WAIT_LGKM0_BAR();

    // ---------------- main loop: grid-stride over batches ----------------
    int it = 0;
    for (int b = bid; b < B; b += 256, ++it) {
        const int cur = it & 1;
        const int bn  = b + 256;

        // own staged x(batch b) complete (also drains last iter's store)
        asm volatile("s_waitcnt vmcnt(0)" ::: "memory");
        __builtin_amdgcn_sched_barrier(0);

        // issue prefetch for batch b+256 into the other buffer; stays in
        // flight across ALL of this iteration's barriers (none drain vmcnt)
        if (bn < B) {
            const float* xs = x + (size_t)bn * 16384;
#pragma unroll
            for (int i = 0; i < 4; ++i)
                GLOAD16(xs + (4 * w + i) * 256 + lane * 4,
                        &xbuf[cur ^ 1][(4 * w + i) * 256]);
        }

        // ---- P1: dots for rows 4w..4w+3 (wave-local x), 16 thr/row ----
        {
            float d2 = 0.f, d3 = 0.f;
            const float* xr = &xbuf[cur][(4 * w + g) * 256 + l15 * 4];
#pragma unroll
            for (int kk = 0; kk < 4; ++kk) {
                f32x4 xv = *(const f32x4*)(xr + kk * 64);
                d2 = fmaf(xv[0], w2v[kk][0], d2); d2 = fmaf(xv[1], w2v[kk][1], d2);
                d2 = fmaf(xv[2], w2v[kk][2], d2); d2 = fmaf(xv[3], w2v[kk][3], d2);
                d3 = fmaf(xv[0], w3v[kk][0], d3); d3 = fmaf(xv[1], w3v[kk][1], d3);
                d3 = fmaf(xv[2], w3v[kk][2], d3); d3 = fmaf(xv[3], w3v[kk][3], d3);
            }
            d2 += __shfl_xor(d2, 1); d2 += __shfl_xor(d2, 2);
            d2 += __shfl_xor(d2, 4); d2 += __shfl_xor(d2, 8);
            d3 += __shfl_xor(d3, 1); d3 += __shfl_xor(d3, 2);
            d3 += __shfl_xor(d3, 4); d3 += __shfl_xor(d3, 8);
            if (l15 == 0) {
                lr2[4 * w + g][0] = d2 * W1v;
                lr2[4 * w + g][1] = d3;
            }
        }
        WAIT_LGKM0_BAR();

        // ---- P3': per-wave in-register t-frags + MFMA (tile rb,cb) ----
        const int n  = 16 * cb + l15;       // t column owned by this lane
        const float rv = lr2[n][1];
        f32x4 acc = (f32x4){0.f, 0.f, 0.f, 0.f};
#pragma unroll
        for (int sk = 0; sk < 2; ++sk) {
            const int jb = 32 * sk + 8 * g;
            bf16x8 Th, Tl;
#pragma unroll
            for (int e = 0; e < 8; ++e) {
                float z  = fmaf(lr2[jb + e][0], rv, xbs[(jb + e) * 65 + n]);
                float e2 = __expf(2.f * z);
                float th = 1.f - __fdividef(2.f, e2 + 1.f);  // tanh, saturates
                __bf16 h = (__bf16)th;
                Th[e] = h;
                Tl[e] = (__bf16)(th - (float)h);
            }
            acc = __builtin_amdgcn_mfma_f32_16x16x32_bf16(Th, Vh[sk], acc, 0, 0, 0);
            acc = __builtin_amdgcn_mfma_f32_16x16x32_bf16(Tl, Vh[sk], acc, 0, 0, 0);
            acc = __builtin_amdgcn_mfma_f32_16x16x32_bf16(Th, Vl[sk], acc, 0, 0, 0);
        }

        // ---- P4: block softmax over the 4096 scores of batch b ----
        float m = fmaxf(fmaxf(acc[0], acc[1]), fmaxf(acc[2], acc[3]));
#pragma unroll
        for (int off = 1; off < 64; off <<= 1) m = fmaxf(m, __shfl_xor(m, off));
        if (lane == 0) redm[w] = m;
        WAIT_LGKM0_BAR();
        float M = redm[l15];
#pragma unroll
        for (int off = 1; off < 16; off <<= 1) M = fmaxf(M, __shfl_xor(M, off));

        float ssum = 0.f;
#pragma unroll
        for (int e = 0; e < 4; ++e) {
            acc[e] = __expf(acc[e] - M);
            ssum += acc[e];
        }
#pragma unroll
        for (int off = 1; off < 64; off <<= 1) ssum += __shfl_xor(ssum, off);
        if (lane == 0) reds[w] = ssum;
        WAIT_LGKM0_BAR();
        float S = reds[l15];
#pragma unroll
        for (int off = 1; off < 16; off <<= 1) S += __shfl_xor(S, off);
        const float inv = __fdividef(1.f, S);

        // ---- store (r4-verified D mapping): s[16rb+l15][16cb+4g .. +3] ----
        f32x4 v = {acc[0] * inv, acc[1] * inv, acc[2] * inv, acc[3] * inv};
        *(f32x4*)(out + (size_t)b * 4096 + (16 * rb + l15) * 64 + 16 * cb + 4 * g) = v;
    }
}

extern "C" void kernel_launch(void* const* d_in, const int* in_sizes, int n_in,
                              void* d_out, int out_size, void* d_ws, size_t ws_size,
                              hipStream_t stream) {
    const float* x  = (const float*)d_in[0];
    const float* W1 = (const float*)d_in[1];
    const float* W2 = (const float*)d_in[2];
    const float* W3 = (const float*)d_in[3];
    const float* bs = (const float*)d_in[4];
    const float* Vs = (const float*)d_in[5];
    float* out = (float*)d_out;

    const int B = in_sizes[0] / (64 * 256);
    const int grid = (B < 256) ? B : 256;
    adjatt_kernel<<<dim3(grid), dim3(1024), 0, stream>>>(x, W1, W2, W3, bs, Vs, out, B);
}

// Round 10
// 68.916 us; speedup vs baseline: 1.6666x; 1.6666x over previous
//
#include <hip/hip_runtime.h>

// AdjacencyAttention: B=4096, N=64, D=256, fp32 in/out.
// r2 structure (best: 69.7us) + serial-path cuts:
//   - bs pre-loaded to regs before P1 (hidden under P1's HBM stream)
//   - operand-swapped MFMA (r4-verified) -> f32x4 stores (16 scalar -> 4 vec)
//   - single-barrier softmax (per-wave m/s + rescale)
// One block (256 threads, 4 waves) per batch element, 4 blocks/CU.

typedef float f32x4 __attribute__((ext_vector_type(4)));
typedef float f32x2 __attribute__((ext_vector_type(2)));
typedef __bf16 bf16x8 __attribute__((ext_vector_type(8)));

__global__ __launch_bounds__(256, 4) void adjatt_kernel(
    const float* __restrict__ x,   // (B,64,256)
    const float* __restrict__ W1,  // (1,)
    const float* __restrict__ W2,  // (256,1)
    const float* __restrict__ W3,  // (256,)
    const float* __restrict__ bs,  // (1,64,64)
    const float* __restrict__ Vs,  // (64,64)
    float* __restrict__ out)       // (B,64,64)
{
    __shared__ __align__(16) unsigned char tT[16384]; // [0,8K): hi bf16 [n][j] swz; [8K,16K): lo
    __shared__ __align__(16) float lhs[64];
    __shared__ __align__(16) float rhs[64];
    __shared__ f32x2 red[4];                          // {m_w, s_w} per wave

    const int tid  = threadIdx.x;
    const int b    = blockIdx.x;
    const int lane = tid & 63;
    const int w    = tid >> 6;
    const int l15  = lane & 15;
    const int g    = lane >> 4;

    const float W1v = W1[0];

    // ---- pre-issue bs loads (consumed in P2; land under P1's streaming) ----
    float bsv[16];
    {
        const int j0 = 16 * w;
        #pragma unroll
        for (int jj = 0; jj < 16; ++jj) bsv[jj] = bs[(j0 + jj) * 64 + lane];
    }

    // ---- Vs fragments (rows 16w..16w+15), hi/lo split; B operand (r4 layout) ----
    // frag: lane l holds M[l15][8g + e], e=0..7 (k-contiguous)
    bf16x8 Vh[2], Vl[2];
    {
        const int row = 16 * w + l15;
        #pragma unroll
        for (int sk = 0; sk < 2; ++sk) {
            const float* vp = Vs + row * 64 + 32 * sk + 8 * g;
            f32x4 f0 = *(const f32x4*)vp;
            f32x4 f1 = *(const f32x4*)(vp + 4);
            #pragma unroll
            for (int e = 0; e < 4; ++e) {
                __bf16 h0 = (__bf16)f0[e];
                Vh[sk][e] = h0;
                Vl[sk][e] = (__bf16)(f0[e] - (float)h0);
                __bf16 h1 = (__bf16)f1[e];
                Vh[sk][e + 4] = h1;
                Vl[sk][e + 4] = (__bf16)(f1[e] - (float)h1);
            }
        }
    }

    // ---- Phase 1: lhs[r] = (x[r,:]·W2)*W1 ; rhs[r] = x[r,:]·W3 (16 thr/row) ----
    {
        const int co = tid & 15;
        const int r0 = tid >> 4;
        f32x4 w2v[4], w3v[4];
        #pragma unroll
        for (int kk = 0; kk < 4; ++kk) {
            w2v[kk] = *(const f32x4*)(W2 + 4 * (co + 16 * kk));
            w3v[kk] = *(const f32x4*)(W3 + 4 * (co + 16 * kk));
        }
        const float* xb = x + (size_t)b * 16384;
        #pragma unroll
        for (int it = 0; it < 4; ++it) {
            const int r = r0 + 16 * it;
            const float* xr = xb + r * 256;
            float d2 = 0.f, d3 = 0.f;
            #pragma unroll
            for (int kk = 0; kk < 4; ++kk) {
                f32x4 xv = *(const f32x4*)(xr + 4 * (co + 16 * kk));
                d2 = fmaf(xv[0], w2v[kk][0], d2); d2 = fmaf(xv[1], w2v[kk][1], d2);
                d2 = fmaf(xv[2], w2v[kk][2], d2); d2 = fmaf(xv[3], w2v[kk][3], d2);
                d3 = fmaf(xv[0], w3v[kk][0], d3); d3 = fmaf(xv[1], w3v[kk][1], d3);
                d3 = fmaf(xv[2], w3v[kk][2], d3); d3 = fmaf(xv[3], w3v[kk][3], d3);
            }
            d2 += __shfl_xor(d2, 1); d2 += __shfl_xor(d2, 2);
            d2 += __shfl_xor(d2, 4); d2 += __shfl_xor(d2, 8);
            d3 += __shfl_xor(d3, 1); d3 += __shfl_xor(d3, 2);
            d3 += __shfl_xor(d3, 4); d3 += __shfl_xor(d3, 8);
            if (co == 0) { lhs[r] = d2 * W1v; rhs[r] = d3; }
        }
    }
    __syncthreads();

    // ---- Phase 2: t[j][n] = tanh(lhs[j]*rhs[n] + bs[j][n]) -> tT[n][j] hi/lo ----
    {
        const int n  = lane;
        const int j0 = 16 * w;
        const float rv = rhs[n];
        f32x4 lh[4];
        #pragma unroll
        for (int c = 0; c < 4; ++c) lh[c] = *(const f32x4*)&lhs[j0 + 4 * c];
        bf16x8 hi[2], lo[2];
        #pragma unroll
        for (int jj = 0; jj < 16; ++jj) {
            float z  = fmaf(lh[jj >> 2][jj & 3], rv, bsv[jj]);
            float e2 = __expf(2.f * z);
            float th = 1.f - __fdividef(2.f, e2 + 1.f);  // tanh, saturates at +/-1
            __bf16 h = (__bf16)th;
            hi[jj >> 3][jj & 7] = h;
            lo[jj >> 3][jj & 7] = (__bf16)(th - (float)h);
        }
        #pragma unroll
        for (int c = 0; c < 2; ++c) {
            const int off = (n * 128 + (j0 + 8 * c) * 2) ^ ((n & 7) << 4);
            *(bf16x8*)(tT + off)        = hi[c];
            *(bf16x8*)(tT + 8192 + off) = lo[c];
        }
    }
    __syncthreads();

    // ---- Phase 3: s^T = t^T @ Vs^T (operand-swapped MFMA, r4-verified) ----
    // acc[ct]: s-rows 16w.. (via Vs frag), s-cols 16ct.. ; 3-product hi/lo split
    f32x4 acc[4];
    #pragma unroll
    for (int ct = 0; ct < 4; ++ct) acc[ct] = (f32x4){0.f, 0.f, 0.f, 0.f};
    #pragma unroll
    for (int ct = 0; ct < 4; ++ct) {
        const int n = 16 * ct + l15;           // t column read by this lane
        #pragma unroll
        for (int sk = 0; sk < 2; ++sk) {
            const int off = (n * 128 + 64 * sk + 16 * g) ^ ((n & 7) << 4);
            bf16x8 Th = *(const bf16x8*)(tT + off);
            bf16x8 Tl = *(const bf16x8*)(tT + 8192 + off);
            acc[ct] = __builtin_amdgcn_mfma_f32_16x16x32_bf16(Th, Vh[sk], acc[ct], 0, 0, 0);
            acc[ct] = __builtin_amdgcn_mfma_f32_16x16x32_bf16(Tl, Vh[sk], acc[ct], 0, 0, 0);
            acc[ct] = __builtin_amdgcn_mfma_f32_16x16x32_bf16(Th, Vl[sk], acc[ct], 0, 0, 0);
        }
    }

    // ---- Phase 4: single-barrier softmax over the 4096 scores ----
    float m = acc[0][0];
    #pragma unroll
    for (int ct = 0; ct < 4; ++ct)
        #pragma unroll
        for (int e = 0; e < 4; ++e) m = fmaxf(m, acc[ct][e]);
    #pragma unroll
    for (int off = 1; off < 64; off <<= 1) m = fmaxf(m, __shfl_xor(m, off));
    // local exp with per-wave max; wave sum
    float ssum = 0.f;
    #pragma unroll
    for (int ct = 0; ct < 4; ++ct)
        #pragma unroll
        for (int e = 0; e < 4; ++e) {
            acc[ct][e] = __expf(acc[ct][e] - m);
            ssum += acc[ct][e];
        }
    #pragma unroll
    for (int off = 1; off < 64; off <<= 1) ssum += __shfl_xor(ssum, off);
    if (lane == 0) red[w] = (f32x2){m, ssum};
    __syncthreads();
    const f32x2 r0v = red[0], r1v = red[1], r2v = red[2], r3v = red[3];
    const float M = fmaxf(fmaxf(r0v[0], r1v[0]), fmaxf(r2v[0], r3v[0]));
    const float S = r0v[1] * __expf(r0v[0] - M) + r1v[1] * __expf(r1v[0] - M) +
                    r2v[1] * __expf(r2v[0] - M) + r3v[1] * __expf(r3v[0] - M);
    const float f = __expf(m - M) * __fdividef(1.f, S);   // per-wave rescale

    // ---- store (r4-verified D mapping): s[16w+l15][16ct+4g .. +3] ----
    float* ob = out + (size_t)b * 4096 + (16 * w + l15) * 64 + 4 * g;
    #pragma unroll
    for (int ct = 0; ct < 4; ++ct) {
        f32x4 v = {acc[ct][0] * f, acc[ct][1] * f, acc[ct][2] * f, acc[ct][3] * f};
        *(f32x4*)(ob + 16 * ct) = v;
    }
}

extern "C" void kernel_launch(void* const* d_in, const int* in_sizes, int n_in,
                              void* d_out, int out_size, void* d_ws, size_t ws_size,
                              hipStream_t stream) {
    const float* x  = (const float*)d_in[0];
    const float* W1 = (const float*)d_in[1];
    const float* W2 = (const float*)d_in[2];
    const float* W3 = (const float*)d_in[3];
    const float* bs = (const float*)d_in[4];
    const float* Vs = (const float*)d_in[5];
    float* out = (float*)d_out;

    const int B = in_sizes[0] / (64 * 256);
    adjatt_kernel<<<dim3(B), dim3(256), 0, stream>>>(x, W1, W2, W3, bs, Vs, out);
}